// Round 2
// baseline (5897.417 us; speedup 1.0000x reference)
//
#include <hip/hip_runtime.h>
#include <hip/hip_fp16.h>
#include <math.h>

#define Nn 200000
#define NNZV 6400000
#define NE 500000
#define HID 256
#define LAT 128

// ---- bf16 helpers (bits in ushort) ----
__device__ __forceinline__ ushort f2bf(float x){
  unsigned b = __float_as_uint(x);
  unsigned r = b + 0x7fffu + ((b >> 16) & 1u);   // RNE
  return (ushort)(r >> 16);
}
__device__ __forceinline__ float bf2f(ushort u){
  return __uint_as_float(((unsigned)u) << 16);
}

// ---------------- CSR build ----------------
__global__ __launch_bounds__(256) void k_zero(int* __restrict__ cnt){
  int i = blockIdx.x*256 + threadIdx.x;
  if(i < Nn) cnt[i] = 0;
}

__global__ __launch_bounds__(256) void k_count(const int* __restrict__ rows, int* __restrict__ cnt){
  int i = blockIdx.x*256 + threadIdx.x;
  if(i < NNZV) atomicAdd(&cnt[rows[i]], 1);
}

__global__ __launch_bounds__(512) void k_scan_block(const int* __restrict__ cnt, int* __restrict__ incl, int* __restrict__ bsum){
  __shared__ int s[512];
  int t = threadIdx.x;
  int i = blockIdx.x*512 + t;
  int v = (i < Nn) ? cnt[i] : 0;
  s[t] = v; __syncthreads();
  for(int off = 1; off < 512; off <<= 1){
    int x = (t >= off) ? s[t-off] : 0;
    __syncthreads();
    s[t] += x;
    __syncthreads();
  }
  if(i < Nn) incl[i] = s[t];
  if(t == 511) bsum[blockIdx.x] = s[t];
}

__global__ __launch_bounds__(512) void k_scan_bsum(int* __restrict__ bsum, int nb){
  __shared__ int s[512];
  int t = threadIdx.x;
  int v = (t < nb) ? bsum[t] : 0;
  s[t] = v; __syncthreads();
  for(int off = 1; off < 512; off <<= 1){
    int x = (t >= off) ? s[t-off] : 0;
    __syncthreads();
    s[t] += x;
    __syncthreads();
  }
  if(t < nb) bsum[t] = s[t] - v;   // exclusive block offsets
}

__global__ __launch_bounds__(256) void k_finish(const int* __restrict__ incl, const int* __restrict__ boff, int* __restrict__ row_ptr){
  int i = blockIdx.x*256 + threadIdx.x;
  if(i < Nn) row_ptr[i+1] = incl[i] + boff[i >> 9];
  if(i == 0) row_ptr[0] = 0;
}

__global__ __launch_bounds__(256) void k_initcur(const int* __restrict__ row_ptr, int* __restrict__ cur){
  int i = blockIdx.x*256 + threadIdx.x;
  if(i < Nn) cur[i] = row_ptr[i];
}

__global__ __launch_bounds__(256) void k_scatter(const int* __restrict__ rows, const int* __restrict__ cols,
    const float* __restrict__ vals, int* __restrict__ cur,
    int* __restrict__ cols_s, __half* __restrict__ vals_s){
  int i = blockIdx.x*256 + threadIdx.x;
  if(i >= NNZV) return;
  int r = rows[i];
  int j = atomicAdd(&cur[r], 1);
  cols_s[j] = cols[i];
  vals_s[j] = __float2half(vals[i]);
}

// ---------------- gate-score constants: c_v = dot(b2_v, Wg_v) + bg_v ----------------
__global__ void k_const(const float* b2p, const float* Wgp, const float* bgp,
                        const float* b2f, const float* Wgf, const float* bgf,
                        const float* b2n, const float* Wgn, const float* bgn,
                        float* c3){
  int l = threadIdx.x;   // 64
  float p = 0.f, f = 0.f, n = 0.f;
  for(int j = l; j < LAT; j += 64){
    p += b2p[j]*Wgp[j];
    f += b2f[j]*Wgf[j];
    n += b2n[j]*Wgn[j];
  }
  #pragma unroll
  for(int off = 32; off >= 1; off >>= 1){
    p += __shfl_xor(p, off);
    f += __shfl_xor(f, off);
    n += __shfl_xor(n, off);
  }
  if(l == 0){ c3[0] = p + bgp[0]; c3[1] = f + bgf[0]; c3[2] = n + bgn[0]; }
}

// ---------------- fused spmm1 + 3 encoders ----------------
// per block: 32 rows. Phase0: sT[32][136] = (A @ [xp|xf|xn])[rows].
// Then per view: hT = relu(sT_v @ W1 + b1); Y_v = hT @ W2 (bf16); yg_v = Y_v @ Wg.
template<int KIN>
__device__ __forceinline__ void encode_view(
    int tid, int row0, int voff,
    const float (*sT)[136], float (*hT)[HID],
    const float* __restrict__ W1, const float* __restrict__ b1,
    const float* __restrict__ W2, const float* __restrict__ Wg,
    ushort* __restrict__ Yv, float* __restrict__ ygv){
  // GEMM1: 32x256 = sT_v[32xKIN] @ W1[KINx256]
  {
    int c0 = (tid & 63) * 4, rg = (tid >> 6) * 8;
    float4 acc[8];
    #pragma unroll
    for(int i = 0; i < 8; i++) acc[i] = make_float4(0.f, 0.f, 0.f, 0.f);
    #pragma unroll 2
    for(int k = 0; k < KIN; k++){
      float4 w = *(const float4*)&W1[k*HID + c0];
      #pragma unroll
      for(int i = 0; i < 8; i++){
        float s = sT[rg + i][voff + k];
        acc[i].x = fmaf(s, w.x, acc[i].x);
        acc[i].y = fmaf(s, w.y, acc[i].y);
        acc[i].z = fmaf(s, w.z, acc[i].z);
        acc[i].w = fmaf(s, w.w, acc[i].w);
      }
    }
    float4 bb = *(const float4*)&b1[c0];
    #pragma unroll
    for(int i = 0; i < 8; i++){
      float4 h;
      h.x = fmaxf(acc[i].x + bb.x, 0.f);
      h.y = fmaxf(acc[i].y + bb.y, 0.f);
      h.z = fmaxf(acc[i].z + bb.z, 0.f);
      h.w = fmaxf(acc[i].w + bb.w, 0.f);
      *(float4*)&hT[rg + i][c0] = h;
    }
  }
  __syncthreads();
  // GEMM2: 32x128 = hT[32x256] @ W2[256x128]; write bf16 Y; yg = Y @ Wg
  {
    int c0 = (tid & 31) * 4, rg = (tid >> 5) * 4;
    float4 acc[4];
    #pragma unroll
    for(int i = 0; i < 4; i++) acc[i] = make_float4(0.f, 0.f, 0.f, 0.f);
    #pragma unroll 2
    for(int k = 0; k < HID; k++){
      float4 w = *(const float4*)&W2[k*LAT + c0];
      #pragma unroll
      for(int i = 0; i < 4; i++){
        float h = hT[rg + i][k];
        acc[i].x = fmaf(h, w.x, acc[i].x);
        acc[i].y = fmaf(h, w.y, acc[i].y);
        acc[i].z = fmaf(h, w.z, acc[i].z);
        acc[i].w = fmaf(h, w.w, acc[i].w);
      }
    }
    float4 wg = *(const float4*)&Wg[c0];
    #pragma unroll
    for(int i = 0; i < 4; i++){
      ushort4 u;
      u.x = f2bf(acc[i].x); u.y = f2bf(acc[i].y);
      u.z = f2bf(acc[i].z); u.w = f2bf(acc[i].w);
      *(ushort4*)&Yv[(size_t)(row0 + rg + i)*LAT + c0] = u;
      float p = acc[i].x*wg.x + acc[i].y*wg.y + acc[i].z*wg.z + acc[i].w*wg.w;
      #pragma unroll
      for(int off = 16; off >= 1; off >>= 1) p += __shfl_xor(p, off);
      if((tid & 31) == 0) ygv[row0 + rg + i] = p;
    }
  }
  __syncthreads();
}

__global__ __launch_bounds__(256) void k_encfused(
    const int* __restrict__ row_ptr, const int* __restrict__ cols_s, const __half* __restrict__ vals_s,
    const float* __restrict__ xp, const float* __restrict__ xf, const float* __restrict__ xn,
    const float* __restrict__ Wp1, const float* __restrict__ bp1, const float* __restrict__ Wp2, const float* __restrict__ Wgp,
    const float* __restrict__ Wf1, const float* __restrict__ bf1, const float* __restrict__ Wf2, const float* __restrict__ Wgf,
    const float* __restrict__ Wn1, const float* __restrict__ bn1, const float* __restrict__ Wn2, const float* __restrict__ Wgn,
    ushort* __restrict__ Yp, ushort* __restrict__ Yf, ushort* __restrict__ Yn,
    float* __restrict__ yg){
  __shared__ float sT[32][136];   // 17.4 KB
  __shared__ float hT[32][HID];   // 32 KB
  int tid = threadIdx.x;
  int lane = tid & 63, wid = tid >> 6;
  int row0 = blockIdx.x * 32;

  // feature-column assignment (concat [xp(62)|xf(37)|xn(37)])
  int t0 = lane, t1 = lane + 64, t2 = lane + 128;
  const float *p0, *p1;
  int s0, o0, o1, o2;
  if(t0 < 62){ p0 = xp; s0 = 62; o0 = t0; } else { p0 = xf; s0 = 37; o0 = t0 - 62; }
  if(t1 < 99){ p1 = xf; o1 = t1 - 62; } else { p1 = xn; o1 = t1 - 99; }
  bool has2 = (t2 < 136);
  o2 = has2 ? (t2 - 99) : 0;

  // phase 0: spmm rows -> sT
  for(int rr8 = 0; rr8 < 8; rr8++){
    int rr = wid*8 + rr8;
    int r = row0 + rr;
    int start = row_ptr[r], end = row_ptr[r+1];
    float a0 = 0.f, a1 = 0.f, a2 = 0.f;
    for(int j0 = start; j0 < end; j0 += 64){
      int m = end - j0; if(m > 64) m = 64;
      int mycol = 0; float myval = 0.f;
      if(lane < m){ mycol = cols_s[j0 + lane]; myval = __half2float(vals_s[j0 + lane]); }
      for(int k = 0; k < m; k++){
        int col = __shfl(mycol, k);
        float val = __shfl(myval, k);
        a0 = fmaf(val, p0[col*s0 + o0], a0);
        a1 = fmaf(val, p1[col*37 + o1], a1);
        if(has2) a2 = fmaf(val, xn[col*37 + o2], a2);
      }
    }
    sT[rr][t0] = a0;
    sT[rr][t1] = a1;
    if(has2) sT[rr][t2] = a2;
  }
  __syncthreads();

  encode_view<62>(tid, row0, 0,  sT, hT, Wp1, bp1, Wp2, Wgp, Yp, yg);
  encode_view<37>(tid, row0, 62, sT, hT, Wf1, bf1, Wf2, Wgf, Yf, yg + Nn);
  encode_view<37>(tid, row0, 99, sT, hT, Wn1, bn1, Wn2, Wgn, Yn, yg + 2*Nn);
}

// ---------------- fused spmm2 + gate softmax + combine -> z (bf16) ----------------
__global__ __launch_bounds__(256) void k_spmm2f(
    const int* __restrict__ row_ptr, const int* __restrict__ cols_s, const __half* __restrict__ vals_s,
    const ushort* __restrict__ Yp, const ushort* __restrict__ Yf, const ushort* __restrict__ Yn,
    const float* __restrict__ yg, const float* __restrict__ c3,
    const float* __restrict__ b2p, const float* __restrict__ b2f, const float* __restrict__ b2n,
    ushort* __restrict__ z){
  int lane = threadIdx.x & 63;
  int r = blockIdx.x*4 + (threadIdx.x >> 6);
  if(r >= Nn) return;
  int start = row_ptr[r], end = row_ptr[r+1];
  int o = lane*2;
  float2 bpv = *(const float2*)&b2p[o];
  float2 bfv = *(const float2*)&b2f[o];
  float2 bnv = *(const float2*)&b2n[o];
  float ap0=0.f, ap1=0.f, af0=0.f, af1=0.f, an0=0.f, an1=0.f;
  float scp=0.f, scf=0.f, scn=0.f;
  for(int j0 = start; j0 < end; j0 += 64){
    int m = end - j0; if(m > 64) m = 64;
    int mycol = 0; float myval = 0.f;
    if(lane < m){
      mycol = cols_s[j0 + lane];
      myval = __half2float(vals_s[j0 + lane]);
      scp = fmaf(myval, yg[mycol], scp);
      scf = fmaf(myval, yg[Nn + mycol], scf);
      scn = fmaf(myval, yg[2*Nn + mycol], scn);
    }
    for(int k = 0; k < m; k++){
      int col = __shfl(mycol, k);
      float val = __shfl(myval, k);
      size_t b = (size_t)col*LAT + o;
      ushort2 up = *(const ushort2*)&Yp[b];
      ushort2 uf = *(const ushort2*)&Yf[b];
      ushort2 un = *(const ushort2*)&Yn[b];
      ap0 = fmaf(val, bf2f(up.x), ap0); ap1 = fmaf(val, bf2f(up.y), ap1);
      af0 = fmaf(val, bf2f(uf.x), af0); af1 = fmaf(val, bf2f(uf.y), af1);
      an0 = fmaf(val, bf2f(un.x), an0); an1 = fmaf(val, bf2f(un.y), an1);
    }
  }
  #pragma unroll
  for(int off = 32; off >= 1; off >>= 1){
    scp += __shfl_xor(scp, off);
    scf += __shfl_xor(scf, off);
    scn += __shfl_xor(scn, off);
  }
  float sp = scp + c3[0], sf = scf + c3[1], sn = scn + c3[2];
  float mx = fmaxf(sp, fmaxf(sf, sn));
  float ep = expf(sp - mx), ef = expf(sf - mx), en = expf(sn - mx);
  float inv = 1.f / (ep + ef + en);
  float A0 = ep*inv, A1 = ef*inv, A2 = en*inv;
  float z0 = A0*(ap0 + bpv.x) + A1*(af0 + bfv.x) + A2*(an0 + bnv.x);
  float z1 = A0*(ap1 + bpv.y) + A1*(af1 + bfv.y) + A2*(an1 + bnv.y);
  ushort2 uz; uz.x = f2bf(z0); uz.y = f2bf(z1);
  *(ushort2*)&z[(size_t)r*LAT + o] = uz;
}

// ---------------- edge decoder ----------------
__global__ __launch_bounds__(256) void k_dec(const ushort* __restrict__ z, const int* __restrict__ esrc,
    const int* __restrict__ edst, const float* __restrict__ Wd1, const float* __restrict__ bd1,
    const float* __restrict__ Wd2, const float* __restrict__ bd2, float* __restrict__ out){
  __shared__ float fT[128][68];   // 34.8 KB
  __shared__ float wT[64][64];    // 16 KB
  __shared__ float red[128][17];  // 8.7 KB
  int tid = threadIdx.x;
  int e0 = blockIdx.x * 128;
  int cg = tid & 15;
  int g  = tid >> 4;
  int c0 = cg * 4;
  float4 acc[8];
  #pragma unroll
  for(int i = 0; i < 8; i++) acc[i] = make_float4(0.f, 0.f, 0.f, 0.f);

  for(int kt = 0; kt < 8; kt++){
    #pragma unroll 4
    for(int i2 = 0; i2 < 16; i2++){
      int lin = i2*256 + tid;
      int kk = lin >> 6, cc = lin & 63;
      wT[kk][cc] = Wd1[(kt*64 + kk)*64 + cc];
    }
    {
      int kk = tid & 63;
      int colo = (kt & 1)*64 + kk;
      int regn = kt >> 1;
      #pragma unroll 4
      for(int i2 = 0; i2 < 32; i2++){
        int e = i2*4 + (tid >> 6);
        int ee = e0 + e; if(ee >= NE) ee = 0;
        float v;
        if(regn == 0)      v = bf2f(z[(size_t)esrc[ee]*LAT + colo]);
        else if(regn == 1) v = bf2f(z[(size_t)edst[ee]*LAT + colo]);
        else {
          float a = bf2f(z[(size_t)esrc[ee]*LAT + colo]);
          float b = bf2f(z[(size_t)edst[ee]*LAT + colo]);
          v = (regn == 2) ? a*b : fabsf(a - b);
        }
        fT[e][kk] = v;
      }
    }
    __syncthreads();
    #pragma unroll 4
    for(int k = 0; k < 64; k += 4){
      float4 w0 = *(const float4*)&wT[k+0][c0];
      float4 w1 = *(const float4*)&wT[k+1][c0];
      float4 w2 = *(const float4*)&wT[k+2][c0];
      float4 w3 = *(const float4*)&wT[k+3][c0];
      #pragma unroll
      for(int i = 0; i < 8; i++){
        float4 f = *(const float4*)&fT[g + 16*i][k];
        acc[i].x = fmaf(f.x, w0.x, fmaf(f.y, w1.x, fmaf(f.z, w2.x, fmaf(f.w, w3.x, acc[i].x))));
        acc[i].y = fmaf(f.x, w0.y, fmaf(f.y, w1.y, fmaf(f.z, w2.y, fmaf(f.w, w3.y, acc[i].y))));
        acc[i].z = fmaf(f.x, w0.z, fmaf(f.y, w1.z, fmaf(f.z, w2.z, fmaf(f.w, w3.z, acc[i].z))));
        acc[i].w = fmaf(f.x, w0.w, fmaf(f.y, w1.w, fmaf(f.z, w2.w, fmaf(f.w, w3.w, acc[i].w))));
      }
    }
    __syncthreads();
  }
  float4 bb  = *(const float4*)&bd1[c0];
  float4 w2v = *(const float4*)&Wd2[c0];
  #pragma unroll
  for(int i = 0; i < 8; i++){
    float hx = fmaxf(acc[i].x + bb.x, 0.f);
    float hy = fmaxf(acc[i].y + bb.y, 0.f);
    float hz = fmaxf(acc[i].z + bb.z, 0.f);
    float hw = fmaxf(acc[i].w + bb.w, 0.f);
    red[g + 16*i][cg] = hx*w2v.x + hy*w2v.y + hz*w2v.z + hw*w2v.w;
  }
  __syncthreads();
  if(tid < 128){
    float s = 0.f;
    #pragma unroll
    for(int q = 0; q < 16; q++) s += red[tid][q];
    int ee = e0 + tid;
    if(ee < NE) out[ee] = s + bd2[0];
  }
}

// ---------------- host ----------------
extern "C" void kernel_launch(void* const* d_in, const int* in_sizes, int n_in,
                              void* d_out, int out_size, void* d_ws, size_t ws_size,
                              hipStream_t stream) {
  const float* xp  = (const float*)d_in[0];
  const float* xf  = (const float*)d_in[1];
  const float* xn  = (const float*)d_in[2];
  const int* arows = (const int*)d_in[3];
  const int* acols = (const int*)d_in[4];
  const float* avals = (const float*)d_in[5];
  const int* esrc  = (const int*)d_in[6];
  const int* edst  = (const int*)d_in[7];
  const float* Wp1 = (const float*)d_in[8];  const float* bp1 = (const float*)d_in[9];
  const float* Wp2 = (const float*)d_in[10]; const float* bp2 = (const float*)d_in[11];
  const float* Wf1 = (const float*)d_in[12]; const float* bf1 = (const float*)d_in[13];
  const float* Wf2 = (const float*)d_in[14]; const float* bf2w = (const float*)d_in[15];
  const float* Wn1 = (const float*)d_in[16]; const float* bn1 = (const float*)d_in[17];
  const float* Wn2 = (const float*)d_in[18]; const float* bn2 = (const float*)d_in[19];
  const float* Wgp = (const float*)d_in[20]; const float* bgp = (const float*)d_in[21];
  const float* Wgf = (const float*)d_in[22]; const float* bgf = (const float*)d_in[23];
  const float* Wgn = (const float*)d_in[24]; const float* bgn = (const float*)d_in[25];
  const float* Wd1 = (const float*)d_in[26]; const float* bd1 = (const float*)d_in[27];
  const float* Wd2 = (const float*)d_in[28]; const float* bd2 = (const float*)d_in[29];
  float* out = (float*)d_out;
  (void)in_sizes; (void)n_in; (void)out_size; (void)ws_size;

  char* base = (char*)d_ws;
  size_t off = 0;
  auto alloc = [&](size_t nbytes) -> char* {
    off = (off + 255) & ~(size_t)255;
    char* p = base + off;
    off += nbytes;
    return p;
  };
  int*    row_ptr = (int*)   alloc((size_t)(Nn + 1) * 4);        // 0.8 MB
  int*    cols_s  = (int*)   alloc((size_t)NNZV * 4);            // 25.6 MB
  __half* vals_s  = (__half*)alloc((size_t)NNZV * 2);            // 12.8 MB
  ushort* Yp      = (ushort*)alloc((size_t)Nn * LAT * 2);        // 51.2 MB
  ushort* Yf      = (ushort*)alloc((size_t)Nn * LAT * 2);        // 51.2 MB
  ushort* Yn      = (ushort*)alloc((size_t)Nn * LAT * 2);        // 51.2 MB
  float*  yg      = (float*) alloc((size_t)3 * Nn * 4);          // 2.4 MB
  float*  c3      = (float*) alloc(256);
  ushort* z       = (ushort*)alloc((size_t)Nn * LAT * 2);        // 51.2 MB
  // CSR-build temporaries aliased into z's region (dead before z is written)
  int* cur  = (int*)((char*)z);
  int* incl = (int*)((char*)z + 800000);
  int* bsum = (int*)((char*)z + 1600000);
  // total ws: ~246.4 MB

  int NB = (Nn + 511) / 512;   // 391

  k_zero   <<<(Nn + 255)/256, 256, 0, stream>>>(cur);
  k_count  <<<(NNZV + 255)/256, 256, 0, stream>>>(arows, cur);
  k_scan_block<<<NB, 512, 0, stream>>>(cur, incl, bsum);
  k_scan_bsum<<<1, 512, 0, stream>>>(bsum, NB);
  k_finish <<<(Nn + 255)/256, 256, 0, stream>>>(incl, bsum, row_ptr);
  k_initcur<<<(Nn + 255)/256, 256, 0, stream>>>(row_ptr, cur);
  k_scatter<<<(NNZV + 255)/256, 256, 0, stream>>>(arows, acols, avals, cur, cols_s, vals_s);

  k_const<<<1, 64, 0, stream>>>(bp2, Wgp, bgp, bf2w, Wgf, bgf, bn2, Wgn, bgn, c3);

  k_encfused<<<Nn/32, 256, 0, stream>>>(row_ptr, cols_s, vals_s, xp, xf, xn,
      Wp1, bp1, Wp2, Wgp,  Wf1, bf1, Wf2, Wgf,  Wn1, bn1, Wn2, Wgn,
      Yp, Yf, Yn, yg);

  k_spmm2f<<<Nn/4, 256, 0, stream>>>(row_ptr, cols_s, vals_s, Yp, Yf, Yn,
      yg, c3, bp2, bf2w, bn2, z);

  k_dec<<<(NE + 127)/128, 256, 0, stream>>>(z, esrc, edst, Wd1, bd1, Wd2, bd2, out);
}

// Round 3
// 4538.543 us; speedup vs baseline: 1.2994x; 1.2994x over previous
//
#include <hip/hip_runtime.h>
#include <math.h>

#define Nn 200000
#define NNZV 6400000
#define NE 500000
#define HID 256
#define LAT 128

typedef _Float16 h2 __attribute__((ext_vector_type(2)));
struct alignas(8) H4 { _Float16 h[4]; };

__device__ __forceinline__ float fdot2(h2 a, h2 b, float c){
  return __builtin_amdgcn_fdot2(a, b, c, false);
}
__device__ __forceinline__ h2 bch2(unsigned u){ return __builtin_bit_cast(h2, u); }

// ---------------- CSR build ----------------
__global__ __launch_bounds__(256) void k_zero(int* __restrict__ cnt){
  int i = blockIdx.x*256 + threadIdx.x;
  if(i < Nn) cnt[i] = 0;
}

__global__ __launch_bounds__(256) void k_count(const int* __restrict__ rows, int* __restrict__ cnt){
  int i = blockIdx.x*256 + threadIdx.x;
  if(i < NNZV) atomicAdd(&cnt[rows[i]], 1);
}

__global__ __launch_bounds__(512) void k_scan_block(const int* __restrict__ cnt, int* __restrict__ incl, int* __restrict__ bsum){
  __shared__ int s[512];
  int t = threadIdx.x;
  int i = blockIdx.x*512 + t;
  int v = (i < Nn) ? cnt[i] : 0;
  s[t] = v; __syncthreads();
  for(int off = 1; off < 512; off <<= 1){
    int x = (t >= off) ? s[t-off] : 0;
    __syncthreads();
    s[t] += x;
    __syncthreads();
  }
  if(i < Nn) incl[i] = s[t];
  if(t == 511) bsum[blockIdx.x] = s[t];
}

__global__ __launch_bounds__(512) void k_scan_bsum(int* __restrict__ bsum, int nb){
  __shared__ int s[512];
  int t = threadIdx.x;
  int v = (t < nb) ? bsum[t] : 0;
  s[t] = v; __syncthreads();
  for(int off = 1; off < 512; off <<= 1){
    int x = (t >= off) ? s[t-off] : 0;
    __syncthreads();
    s[t] += x;
    __syncthreads();
  }
  if(t < nb) bsum[t] = s[t] - v;
}

__global__ __launch_bounds__(256) void k_finish(const int* __restrict__ incl, const int* __restrict__ boff, int* __restrict__ row_ptr){
  int i = blockIdx.x*256 + threadIdx.x;
  if(i < Nn) row_ptr[i+1] = incl[i] + boff[i >> 9];
  if(i == 0) row_ptr[0] = 0;
}

__global__ __launch_bounds__(256) void k_initcur(const int* __restrict__ row_ptr, int* __restrict__ cur){
  int i = blockIdx.x*256 + threadIdx.x;
  if(i < Nn) cur[i] = row_ptr[i];
}

__global__ __launch_bounds__(256) void k_scatter(const int* __restrict__ rows, const int* __restrict__ cols,
    const float* __restrict__ vals, int* __restrict__ cur,
    int* __restrict__ cols_s, _Float16* __restrict__ vals_s){
  int i = blockIdx.x*256 + threadIdx.x;
  if(i >= NNZV) return;
  int r = rows[i];
  int j = atomicAdd(&cur[r], 1);
  cols_s[j] = cols[i];
  vals_s[j] = (_Float16)vals[i];
}

// ---------------- feature pack: xcat[N][144] fp16 = [xp(62)|xf(37)|0|xn(37)|0 pad] ----------------
__global__ __launch_bounds__(256) void k_xpack(const float* __restrict__ xp, const float* __restrict__ xf,
    const float* __restrict__ xn, _Float16* __restrict__ xc){
  int idx = blockIdx.x*256 + threadIdx.x;   // N*36
  int row = idx/36, c4 = idx - row*36;
  int cb = c4*4;
  H4 h;
  #pragma unroll
  for(int q = 0; q < 4; q++){
    int c = cb + q;
    float x;
    if(c < 62)       x = xp[row*62 + c];
    else if(c < 99)  x = xf[row*37 + (c-62)];
    else if(c == 99) x = 0.f;
    else if(c < 137) x = xn[row*37 + (c-100)];
    else             x = 0.f;
    h.h[q] = (_Float16)x;
  }
  *(H4*)&xc[row*144 + cb] = h;
}

// ---------------- weight pack: fp32 [K][C] -> fp16 k-pair packed [ceil(K/2)][C] ----------------
__global__ __launch_bounds__(256) void k_wpack(
    const float* __restrict__ Wp1, const float* __restrict__ Wf1, const float* __restrict__ Wn1,
    const float* __restrict__ Wp2, const float* __restrict__ Wf2, const float* __restrict__ Wn2,
    h2* __restrict__ w1p, h2* __restrict__ w1f, h2* __restrict__ w1n,
    h2* __restrict__ w2p, h2* __restrict__ w2f, h2* __restrict__ w2n){
  int i = blockIdx.x*256 + threadIdx.x;
  const float* src; h2* dst; int K, C, idx;
  if(i < 7936)      { src=Wp1; dst=w1p; K=62;  C=256; idx=i; }
  else if(i < 12800){ src=Wf1; dst=w1f; K=37;  C=256; idx=i-7936; }
  else if(i < 17664){ src=Wn1; dst=w1n; K=37;  C=256; idx=i-12800; }
  else if(i < 34048){ src=Wp2; dst=w2p; K=256; C=128; idx=i-17664; }
  else if(i < 50432){ src=Wf2; dst=w2f; K=256; C=128; idx=i-34048; }
  else if(i < 66816){ src=Wn2; dst=w2n; K=256; C=128; idx=i-50432; }
  else return;
  int j = idx / C, c = idx - j*C;
  float a = src[(2*j)*C + c];
  float b = (2*j+1 < K) ? src[(2*j+1)*C + c] : 0.f;
  h2 r; r[0] = (_Float16)a; r[1] = (_Float16)b;
  dst[idx] = r;
}

// ---------------- gate-score constants ----------------
__global__ void k_const(const float* b2p, const float* Wgp, const float* bgp,
                        const float* b2f, const float* Wgf, const float* bgf,
                        const float* b2n, const float* Wgn, const float* bgn,
                        float* c3){
  int l = threadIdx.x;
  float p = 0.f, f = 0.f, n = 0.f;
  for(int j = l; j < LAT; j += 64){
    p += b2p[j]*Wgp[j];
    f += b2f[j]*Wgf[j];
    n += b2n[j]*Wgn[j];
  }
  #pragma unroll
  for(int off = 32; off >= 1; off >>= 1){
    p += __shfl_xor(p, off);
    f += __shfl_xor(f, off);
    n += __shfl_xor(n, off);
  }
  if(l == 0){ c3[0] = p + bgp[0]; c3[1] = f + bgf[0]; c3[2] = n + bgn[0]; }
}

// ---------------- encoder view (dot2-based GEMMs) ----------------
template<int NPAIR>
__device__ __forceinline__ void encode_view(
    int tid, int row0, int voff, int vidx,
    const _Float16 (*sT)[144], _Float16 (*hT)[HID],
    const h2* __restrict__ W1h, const float* __restrict__ b1,
    const h2* __restrict__ W2h, const float* __restrict__ Wg,
    _Float16* __restrict__ Yv, float* __restrict__ yg4f){
  // GEMM1: 32xHID = sT_v[32 x 2*NPAIR] @ W1
  {
    int c0 = (tid & 63)*4, rg = (tid >> 6)*8;
    float4 acc[8];
    #pragma unroll
    for(int i = 0; i < 8; i++) acc[i] = make_float4(0.f,0.f,0.f,0.f);
    for(int j = 0; j < NPAIR; j++){
      uint4 wv = *(const uint4*)&W1h[j*HID + c0];
      h2 w0 = bch2(wv.x), w1 = bch2(wv.y), w2 = bch2(wv.z), w3 = bch2(wv.w);
      #pragma unroll
      for(int i = 0; i < 8; i++){
        h2 s2 = *(const h2*)&sT[rg + i][voff + 2*j];
        acc[i].x = fdot2(s2, w0, acc[i].x);
        acc[i].y = fdot2(s2, w1, acc[i].y);
        acc[i].z = fdot2(s2, w2, acc[i].z);
        acc[i].w = fdot2(s2, w3, acc[i].w);
      }
    }
    float4 bb = *(const float4*)&b1[c0];
    #pragma unroll
    for(int i = 0; i < 8; i++){
      float h0 = fmaxf(acc[i].x + bb.x, 0.f);
      float h1 = fmaxf(acc[i].y + bb.y, 0.f);
      float h2v = fmaxf(acc[i].z + bb.z, 0.f);
      float h3 = fmaxf(acc[i].w + bb.w, 0.f);
      h2 t0; t0[0] = (_Float16)h0; t0[1] = (_Float16)h1;
      h2 t1; t1[0] = (_Float16)h2v; t1[1] = (_Float16)h3;
      *(h2*)&hT[rg + i][c0]     = t0;
      *(h2*)&hT[rg + i][c0 + 2] = t1;
    }
  }
  __syncthreads();
  // GEMM2: 32xLAT = hT[32xHID] @ W2; Y fp16; yg = Y @ Wg
  {
    int c0 = (tid & 31)*4, rg = (tid >> 5)*4;
    float4 acc[4];
    #pragma unroll
    for(int i = 0; i < 4; i++) acc[i] = make_float4(0.f,0.f,0.f,0.f);
    for(int k2 = 0; k2 < HID/2; k2++){
      uint4 wv = *(const uint4*)&W2h[k2*LAT + c0];
      h2 w0 = bch2(wv.x), w1 = bch2(wv.y), w2 = bch2(wv.z), w3 = bch2(wv.w);
      #pragma unroll
      for(int i = 0; i < 4; i++){
        h2 hh = *(const h2*)&hT[rg + i][2*k2];
        acc[i].x = fdot2(hh, w0, acc[i].x);
        acc[i].y = fdot2(hh, w1, acc[i].y);
        acc[i].z = fdot2(hh, w2, acc[i].z);
        acc[i].w = fdot2(hh, w3, acc[i].w);
      }
    }
    float4 wg = *(const float4*)&Wg[c0];
    #pragma unroll
    for(int i = 0; i < 4; i++){
      int row = row0 + rg + i;
      h2 t0; t0[0] = (_Float16)acc[i].x; t0[1] = (_Float16)acc[i].y;
      h2 t1; t1[0] = (_Float16)acc[i].z; t1[1] = (_Float16)acc[i].w;
      *(h2*)&Yv[(size_t)row*LAT + c0]     = t0;
      *(h2*)&Yv[(size_t)row*LAT + c0 + 2] = t1;
      float p = acc[i].x*wg.x + acc[i].y*wg.y + acc[i].z*wg.z + acc[i].w*wg.w;
      #pragma unroll
      for(int off = 16; off >= 1; off >>= 1) p += __shfl_xor(p, off);
      if((tid & 31) == 0) yg4f[(size_t)row*4 + vidx] = p;
    }
  }
  __syncthreads();
}

// ---------------- fused spmm1 + 3 encoders ----------------
__global__ __launch_bounds__(256, 5) void k_encfused(
    const int* __restrict__ row_ptr, const int* __restrict__ cols_s, const _Float16* __restrict__ vals_s,
    const _Float16* __restrict__ xc,
    const h2* __restrict__ w1p, const float* __restrict__ bp1, const h2* __restrict__ w2p, const float* __restrict__ Wgp,
    const h2* __restrict__ w1f, const float* __restrict__ bf1, const h2* __restrict__ w2f, const float* __restrict__ Wgf,
    const h2* __restrict__ w1n, const float* __restrict__ bn1, const h2* __restrict__ w2n, const float* __restrict__ Wgn,
    _Float16* __restrict__ Yp, _Float16* __restrict__ Yf, _Float16* __restrict__ Yn,
    float* __restrict__ yg4f){
  __shared__ _Float16 sT[32][144];   // 9.2 KB
  __shared__ _Float16 hT[32][HID];   // 16 KB
  int tid = threadIdx.x;
  int lane = tid & 63, wid = tid >> 6;
  int row0 = blockIdx.x * 32;
  bool has2 = (lane < 16);

  // phase 0: gather-spmm rows -> sT (fp16)
  for(int rr8 = 0; rr8 < 8; rr8++){
    int r = row0 + wid*8 + rr8;
    int start = row_ptr[r], end = row_ptr[r+1];
    float a0 = 0.f, a1 = 0.f, a2 = 0.f;
    for(int j0 = start; j0 < end; j0 += 64){
      int m = end - j0; if(m > 64) m = 64;
      int mycol = 0; float myval = 0.f;
      if(lane < m){ mycol = cols_s[j0 + lane]; myval = (float)vals_s[j0 + lane]; }
      int mpad = (m + 3) & ~3;
      for(int k = 0; k < mpad; k += 4){
        #pragma unroll
        for(int q = 0; q < 4; q++){
          int c = __shfl(mycol, k + q);
          float v = __shfl(myval, k + q);
          const _Float16* xr = &xc[(size_t)c*144];
          float x0 = (float)xr[lane];
          float x1 = (float)xr[64 + lane];
          a0 = fmaf(v, x0, a0);
          a1 = fmaf(v, x1, a1);
          if(has2){
            float x2 = (float)xr[128 + lane];
            a2 = fmaf(v, x2, a2);
          }
        }
      }
    }
    int rr = wid*8 + rr8;
    sT[rr][lane]      = (_Float16)a0;
    sT[rr][64 + lane] = (_Float16)a1;
    if(has2) sT[rr][128 + lane] = (_Float16)a2;
  }
  __syncthreads();

  encode_view<31>(tid, row0, 0,   0, sT, hT, w1p, bp1, w2p, Wgp, Yp, yg4f);
  encode_view<19>(tid, row0, 62,  1, sT, hT, w1f, bf1, w2f, Wgf, Yf, yg4f);
  encode_view<19>(tid, row0, 100, 2, sT, hT, w1n, bn1, w2n, Wgn, Yn, yg4f);
}

// ---------------- fused spmm2 + gate softmax + combine -> z (fp16) ----------------
__global__ __launch_bounds__(256) void k_spmm2f(
    const int* __restrict__ row_ptr, const int* __restrict__ cols_s, const _Float16* __restrict__ vals_s,
    const _Float16* __restrict__ Yp, const _Float16* __restrict__ Yf, const _Float16* __restrict__ Yn,
    const float4* __restrict__ yg4, const float* __restrict__ c3,
    const float* __restrict__ b2p, const float* __restrict__ b2f, const float* __restrict__ b2n,
    _Float16* __restrict__ z){
  int tid = threadIdx.x;
  int hl = tid & 31;
  int base = tid & 32;                 // broadcast base within wave
  int r = blockIdx.x*8 + (tid >> 5);   // 8 rows/block, half-wave per row
  int start = row_ptr[r], end = row_ptr[r+1];
  int o = hl*4;
  float ap0=0,ap1=0,ap2=0,ap3=0, af0=0,af1=0,af2=0,af3=0, an0=0,an1=0,an2=0,an3=0;
  float scp=0.f, scf=0.f, scn=0.f;
  for(int j0 = start; j0 < end; j0 += 32){
    int m = end - j0; if(m > 32) m = 32;
    int mycol = 0; float myval = 0.f;
    if(hl < m){
      mycol = cols_s[j0 + hl];
      myval = (float)vals_s[j0 + hl];
      float4 g = yg4[mycol];
      scp = fmaf(myval, g.x, scp);
      scf = fmaf(myval, g.y, scf);
      scn = fmaf(myval, g.z, scn);
    }
    int mpad = (m + 1) & ~1;
    for(int k = 0; k < mpad; k += 2){
      #pragma unroll
      for(int q = 0; q < 2; q++){
        int c = __shfl(mycol, base + k + q);
        float v = __shfl(myval, base + k + q);
        size_t b = (size_t)c*LAT + o;
        uint2 rp = *(const uint2*)&Yp[b];
        uint2 rf = *(const uint2*)&Yf[b];
        uint2 rn = *(const uint2*)&Yn[b];
        h2 pl = bch2(rp.x), ph = bch2(rp.y);
        h2 fl = bch2(rf.x), fh = bch2(rf.y);
        h2 nl = bch2(rn.x), nh = bch2(rn.y);
        ap0 = fmaf(v, (float)pl[0], ap0); ap1 = fmaf(v, (float)pl[1], ap1);
        ap2 = fmaf(v, (float)ph[0], ap2); ap3 = fmaf(v, (float)ph[1], ap3);
        af0 = fmaf(v, (float)fl[0], af0); af1 = fmaf(v, (float)fl[1], af1);
        af2 = fmaf(v, (float)fh[0], af2); af3 = fmaf(v, (float)fh[1], af3);
        an0 = fmaf(v, (float)nl[0], an0); an1 = fmaf(v, (float)nl[1], an1);
        an2 = fmaf(v, (float)nh[0], an2); an3 = fmaf(v, (float)nh[1], an3);
      }
    }
  }
  #pragma unroll
  for(int off = 16; off >= 1; off >>= 1){
    scp += __shfl_xor(scp, off);
    scf += __shfl_xor(scf, off);
    scn += __shfl_xor(scn, off);
  }
  float sp = scp + c3[0], sf = scf + c3[1], sn = scn + c3[2];
  float mx = fmaxf(sp, fmaxf(sf, sn));
  float ep = expf(sp - mx), ef = expf(sf - mx), en = expf(sn - mx);
  float inv = 1.f / (ep + ef + en);
  float A0 = ep*inv, A1 = ef*inv, A2 = en*inv;
  float4 bp = *(const float4*)&b2p[o];
  float4 bf = *(const float4*)&b2f[o];
  float4 bn = *(const float4*)&b2n[o];
  float z0 = A0*(ap0 + bp.x) + A1*(af0 + bf.x) + A2*(an0 + bn.x);
  float z1 = A0*(ap1 + bp.y) + A1*(af1 + bf.y) + A2*(an1 + bn.y);
  float z2 = A0*(ap2 + bp.z) + A1*(af2 + bf.z) + A2*(an2 + bn.z);
  float z3 = A0*(ap3 + bp.w) + A1*(af3 + bf.w) + A2*(an3 + bn.w);
  H4 out;
  out.h[0] = (_Float16)z0; out.h[1] = (_Float16)z1;
  out.h[2] = (_Float16)z2; out.h[3] = (_Float16)z3;
  *(H4*)&z[(size_t)r*LAT + o] = out;
}

// ---------------- edge decoder ----------------
__global__ __launch_bounds__(256) void k_dec(const _Float16* __restrict__ z, const int* __restrict__ esrc,
    const int* __restrict__ edst, const float* __restrict__ Wd1, const float* __restrict__ bd1,
    const float* __restrict__ Wd2, const float* __restrict__ bd2, float* __restrict__ out){
  __shared__ float fT[128][68];
  __shared__ float wT[64][64];
  __shared__ float red[128][17];
  int tid = threadIdx.x;
  int e0 = blockIdx.x * 128;
  int cg = tid & 15;
  int g  = tid >> 4;
  int c0 = cg * 4;
  float4 acc[8];
  #pragma unroll
  for(int i = 0; i < 8; i++) acc[i] = make_float4(0.f,0.f,0.f,0.f);

  for(int kt = 0; kt < 8; kt++){
    #pragma unroll 4
    for(int i2 = 0; i2 < 16; i2++){
      int lin = i2*256 + tid;
      int kk = lin >> 6, cc = lin & 63;
      wT[kk][cc] = Wd1[(kt*64 + kk)*64 + cc];
    }
    {
      int kk = tid & 63;
      int colo = (kt & 1)*64 + kk;
      int regn = kt >> 1;
      #pragma unroll 4
      for(int i2 = 0; i2 < 32; i2++){
        int e = i2*4 + (tid >> 6);
        int ee = e0 + e; if(ee >= NE) ee = 0;
        float v;
        if(regn == 0)      v = (float)z[(size_t)esrc[ee]*LAT + colo];
        else if(regn == 1) v = (float)z[(size_t)edst[ee]*LAT + colo];
        else {
          float a = (float)z[(size_t)esrc[ee]*LAT + colo];
          float b = (float)z[(size_t)edst[ee]*LAT + colo];
          v = (regn == 2) ? a*b : fabsf(a - b);
        }
        fT[e][kk] = v;
      }
    }
    __syncthreads();
    #pragma unroll 4
    for(int k = 0; k < 64; k += 4){
      float4 w0 = *(const float4*)&wT[k+0][c0];
      float4 w1 = *(const float4*)&wT[k+1][c0];
      float4 w2 = *(const float4*)&wT[k+2][c0];
      float4 w3 = *(const float4*)&wT[k+3][c0];
      #pragma unroll
      for(int i = 0; i < 8; i++){
        float4 f = *(const float4*)&fT[g + 16*i][k];
        acc[i].x = fmaf(f.x, w0.x, fmaf(f.y, w1.x, fmaf(f.z, w2.x, fmaf(f.w, w3.x, acc[i].x))));
        acc[i].y = fmaf(f.x, w0.y, fmaf(f.y, w1.y, fmaf(f.z, w2.y, fmaf(f.w, w3.y, acc[i].y))));
        acc[i].z = fmaf(f.x, w0.z, fmaf(f.y, w1.z, fmaf(f.z, w2.z, fmaf(f.w, w3.z, acc[i].z))));
        acc[i].w = fmaf(f.x, w0.w, fmaf(f.y, w1.w, fmaf(f.z, w2.w, fmaf(f.w, w3.w, acc[i].w))));
      }
    }
    __syncthreads();
  }
  float4 bb  = *(const float4*)&bd1[c0];
  float4 w2v = *(const float4*)&Wd2[c0];
  #pragma unroll
  for(int i = 0; i < 8; i++){
    float hx = fmaxf(acc[i].x + bb.x, 0.f);
    float hy = fmaxf(acc[i].y + bb.y, 0.f);
    float hz = fmaxf(acc[i].z + bb.z, 0.f);
    float hw = fmaxf(acc[i].w + bb.w, 0.f);
    red[g + 16*i][cg] = hx*w2v.x + hy*w2v.y + hz*w2v.z + hw*w2v.w;
  }
  __syncthreads();
  if(tid < 128){
    float s = 0.f;
    #pragma unroll
    for(int q = 0; q < 16; q++) s += red[tid][q];
    int ee = e0 + tid;
    if(ee < NE) out[ee] = s + bd2[0];
  }
}

// ---------------- host ----------------
extern "C" void kernel_launch(void* const* d_in, const int* in_sizes, int n_in,
                              void* d_out, int out_size, void* d_ws, size_t ws_size,
                              hipStream_t stream) {
  const float* xp  = (const float*)d_in[0];
  const float* xf  = (const float*)d_in[1];
  const float* xn  = (const float*)d_in[2];
  const int* arows = (const int*)d_in[3];
  const int* acols = (const int*)d_in[4];
  const float* avals = (const float*)d_in[5];
  const int* esrc  = (const int*)d_in[6];
  const int* edst  = (const int*)d_in[7];
  const float* Wp1 = (const float*)d_in[8];  const float* bp1 = (const float*)d_in[9];
  const float* Wp2 = (const float*)d_in[10]; const float* bp2 = (const float*)d_in[11];
  const float* Wf1 = (const float*)d_in[12]; const float* bf1 = (const float*)d_in[13];
  const float* Wf2 = (const float*)d_in[14]; const float* bf2w = (const float*)d_in[15];
  const float* Wn1 = (const float*)d_in[16]; const float* bn1 = (const float*)d_in[17];
  const float* Wn2 = (const float*)d_in[18]; const float* bn2 = (const float*)d_in[19];
  const float* Wgp = (const float*)d_in[20]; const float* bgp = (const float*)d_in[21];
  const float* Wgf = (const float*)d_in[22]; const float* bgf = (const float*)d_in[23];
  const float* Wgn = (const float*)d_in[24]; const float* bgn = (const float*)d_in[25];
  const float* Wd1 = (const float*)d_in[26]; const float* bd1 = (const float*)d_in[27];
  const float* Wd2 = (const float*)d_in[28]; const float* bd2 = (const float*)d_in[29];
  float* out = (float*)d_out;
  (void)in_sizes; (void)n_in; (void)out_size; (void)ws_size;

  char* base = (char*)d_ws;
  size_t off = 0;
  auto alloc = [&](size_t nbytes) -> char* {
    off = (off + 255) & ~(size_t)255;
    char* p = base + off;
    off += nbytes;
    return p;
  };
  int*      row_ptr = (int*)     alloc((size_t)(Nn + 1) * 4);   // 0.8 MB
  int*      cols_s  = (int*)     alloc((size_t)NNZV * 4);       // 25.6 MB
  _Float16* vals_s  = (_Float16*)alloc((size_t)NNZV * 2);       // 12.8 MB
  _Float16* xcat    = (_Float16*)alloc((size_t)Nn * 144 * 2);   // 57.6 MB (aliases z + CSR temps)
  _Float16* Yp      = (_Float16*)alloc((size_t)Nn * LAT * 2);   // 51.2 MB
  _Float16* Yf      = (_Float16*)alloc((size_t)Nn * LAT * 2);   // 51.2 MB
  _Float16* Yn      = (_Float16*)alloc((size_t)Nn * LAT * 2);   // 51.2 MB
  float*    yg4     = (float*)   alloc((size_t)Nn * 4 * 4);     // 3.2 MB
  float*    c3      = (float*)   alloc(256);
  h2* w1p = (h2*)alloc(7936*4);  h2* w1f = (h2*)alloc(4864*4);  h2* w1n = (h2*)alloc(4864*4);
  h2* w2p = (h2*)alloc(16384*4); h2* w2f = (h2*)alloc(16384*4); h2* w2n = (h2*)alloc(16384*4);
  // z aliases xcat (xcat dead after k_encfused); CSR temps alias xcat (dead before k_xpack)
  _Float16* z = xcat;
  int* cur  = (int*)((char*)xcat);
  int* incl = (int*)((char*)xcat + 1000000);
  int* bsum = (int*)((char*)xcat + 2000000);
  // total ws: ~254 MB

  int NB = (Nn + 511) / 512;

  k_zero   <<<(Nn + 255)/256, 256, 0, stream>>>(cur);
  k_count  <<<(NNZV + 255)/256, 256, 0, stream>>>(arows, cur);
  k_scan_block<<<NB, 512, 0, stream>>>(cur, incl, bsum);
  k_scan_bsum<<<1, 512, 0, stream>>>(bsum, NB);
  k_finish <<<(Nn + 255)/256, 256, 0, stream>>>(incl, bsum, row_ptr);
  k_initcur<<<(Nn + 255)/256, 256, 0, stream>>>(row_ptr, cur);
  k_scatter<<<(NNZV + 255)/256, 256, 0, stream>>>(arows, acols, avals, cur, cols_s, vals_s);

  k_xpack<<<(Nn*36 + 255)/256, 256, 0, stream>>>(xp, xf, xn, xcat);
  k_wpack<<<(66816 + 255)/256, 256, 0, stream>>>(Wp1, Wf1, Wn1, Wp2, Wf2, Wn2,
                                                 w1p, w1f, w1n, w2p, w2f, w2n);
  k_const<<<1, 64, 0, stream>>>(bp2, Wgp, bgp, bf2w, Wgf, bgf, bn2, Wgn, bgn, c3);

  k_encfused<<<Nn/32, 256, 0, stream>>>(row_ptr, cols_s, vals_s, xcat,
      w1p, bp1, w2p, Wgp,  w1f, bf1, w2f, Wgf,  w1n, bn1, w2n, Wgn,
      Yp, Yf, Yn, yg4);

  k_spmm2f<<<Nn/8, 256, 0, stream>>>(row_ptr, cols_s, vals_s, Yp, Yf, Yn,
      (const float4*)yg4, c3, bp2, bf2w, bn2, z);

  k_dec<<<(NE + 127)/128, 256, 0, stream>>>(z, esrc, edst, Wd1, bd1, Wd2, bd2, out);
}

// Round 4
// 2618.121 us; speedup vs baseline: 2.2525x; 1.7335x over previous
//
#include <hip/hip_runtime.h>
#include <math.h>

#define Nn 200000
#define NNZV 6400000
#define NE 500000
#define HID 256
#define LAT 128

typedef _Float16 h2 __attribute__((ext_vector_type(2)));
typedef _Float16 f16x8 __attribute__((ext_vector_type(8)));
typedef float f32x4 __attribute__((ext_vector_type(4)));
typedef short s16x8 __attribute__((ext_vector_type(8)));
struct alignas(8) H4 { _Float16 h[4]; };

__device__ __forceinline__ float fdot2(h2 a, h2 b, float c){
  return __builtin_amdgcn_fdot2(a, b, c, false);
}
__device__ __forceinline__ h2 bch2(unsigned u){ return __builtin_bit_cast(h2, u); }

// ---------------- CSR build ----------------
__global__ __launch_bounds__(256) void k_zero(int* __restrict__ cnt){
  int i = blockIdx.x*256 + threadIdx.x;
  if(i < Nn) cnt[i] = 0;
}

__global__ __launch_bounds__(256) void k_count(const int* __restrict__ rows, int* __restrict__ cnt){
  int i = blockIdx.x*256 + threadIdx.x;
  if(i < NNZV) atomicAdd(&cnt[rows[i]], 1);
}

__global__ __launch_bounds__(512) void k_scan_block(const int* __restrict__ cnt, int* __restrict__ incl, int* __restrict__ bsum){
  __shared__ int s[512];
  int t = threadIdx.x;
  int i = blockIdx.x*512 + t;
  int v = (i < Nn) ? cnt[i] : 0;
  s[t] = v; __syncthreads();
  for(int off = 1; off < 512; off <<= 1){
    int x = (t >= off) ? s[t-off] : 0;
    __syncthreads();
    s[t] += x;
    __syncthreads();
  }
  if(i < Nn) incl[i] = s[t];
  if(t == 511) bsum[blockIdx.x] = s[t];
}

__global__ __launch_bounds__(512) void k_scan_bsum(int* __restrict__ bsum, int nb){
  __shared__ int s[512];
  int t = threadIdx.x;
  int v = (t < nb) ? bsum[t] : 0;
  s[t] = v; __syncthreads();
  for(int off = 1; off < 512; off <<= 1){
    int x = (t >= off) ? s[t-off] : 0;
    __syncthreads();
    s[t] += x;
    __syncthreads();
  }
  if(t < nb) bsum[t] = s[t] - v;
}

__global__ __launch_bounds__(256) void k_finish(const int* __restrict__ incl, const int* __restrict__ boff, int* __restrict__ row_ptr){
  int i = blockIdx.x*256 + threadIdx.x;
  if(i < Nn) row_ptr[i+1] = incl[i] + boff[i >> 9];
  if(i == 0) row_ptr[0] = 0;
}

__global__ __launch_bounds__(256) void k_initcur(const int* __restrict__ row_ptr, int* __restrict__ cur){
  int i = blockIdx.x*256 + threadIdx.x;
  if(i < Nn) cur[i] = row_ptr[i];
}

__global__ __launch_bounds__(256) void k_scatter(const int* __restrict__ rows, const int* __restrict__ cols,
    const float* __restrict__ vals, int* __restrict__ cur,
    int* __restrict__ cols_s, _Float16* __restrict__ vals_s){
  int i = blockIdx.x*256 + threadIdx.x;
  if(i >= NNZV) return;
  int r = rows[i];
  int j = atomicAdd(&cur[r], 1);
  cols_s[j] = cols[i];
  vals_s[j] = (_Float16)vals[i];
}

// ---------------- feature pack: xcat[N][144] fp16 = [xp(62)|xf(37)|0|xn(37)|0 pad] ----------------
__global__ __launch_bounds__(256) void k_xpack(const float* __restrict__ xp, const float* __restrict__ xf,
    const float* __restrict__ xn, _Float16* __restrict__ xc){
  int idx = blockIdx.x*256 + threadIdx.x;   // N*36
  int row = idx/36, c4 = idx - row*36;
  int cb = c4*4;
  H4 h;
  #pragma unroll
  for(int q = 0; q < 4; q++){
    int c = cb + q;
    float x;
    if(c < 62)       x = xp[row*62 + c];
    else if(c < 99)  x = xf[row*37 + (c-62)];
    else if(c == 99) x = 0.f;
    else if(c < 137) x = xn[row*37 + (c-100)];
    else             x = 0.f;
    h.h[q] = (_Float16)x;
  }
  *(H4*)&xc[row*144 + cb] = h;
}

// ---------------- weight pack: fp32 [K][C] -> fp16 k-pair packed [ceil(K/2)][C] ----------------
__global__ __launch_bounds__(256) void k_wpack(
    const float* __restrict__ Wp1, const float* __restrict__ Wf1, const float* __restrict__ Wn1,
    const float* __restrict__ Wp2, const float* __restrict__ Wf2, const float* __restrict__ Wn2,
    h2* __restrict__ w1p, h2* __restrict__ w1f, h2* __restrict__ w1n,
    h2* __restrict__ w2p, h2* __restrict__ w2f, h2* __restrict__ w2n){
  int i = blockIdx.x*256 + threadIdx.x;
  const float* src; h2* dst; int K, C, idx;
  if(i < 7936)      { src=Wp1; dst=w1p; K=62;  C=256; idx=i; }
  else if(i < 12800){ src=Wf1; dst=w1f; K=37;  C=256; idx=i-7936; }
  else if(i < 17664){ src=Wn1; dst=w1n; K=37;  C=256; idx=i-12800; }
  else if(i < 34048){ src=Wp2; dst=w2p; K=256; C=128; idx=i-17664; }
  else if(i < 50432){ src=Wf2; dst=w2f; K=256; C=128; idx=i-34048; }
  else if(i < 66816){ src=Wn2; dst=w2n; K=256; C=128; idx=i-50432; }
  else return;
  int j = idx / C, c = idx - j*C;
  float a = src[(2*j)*C + c];
  float b = (2*j+1 < K) ? src[(2*j+1)*C + c] : 0.f;
  h2 r; r[0] = (_Float16)a; r[1] = (_Float16)b;
  dst[idx] = r;
}

// ---------------- gate-score constants ----------------
__global__ void k_const(const float* b2p, const float* Wgp, const float* bgp,
                        const float* b2f, const float* Wgf, const float* bgf,
                        const float* b2n, const float* Wgn, const float* bgn,
                        float* c3){
  int l = threadIdx.x;
  float p = 0.f, f = 0.f, n = 0.f;
  for(int j = l; j < LAT; j += 64){
    p += b2p[j]*Wgp[j];
    f += b2f[j]*Wgf[j];
    n += b2n[j]*Wgn[j];
  }
  #pragma unroll
  for(int off = 32; off >= 1; off >>= 1){
    p += __shfl_xor(p, off);
    f += __shfl_xor(f, off);
    n += __shfl_xor(n, off);
  }
  if(l == 0){ c3[0] = p + bgp[0]; c3[1] = f + bgf[0]; c3[2] = n + bgn[0]; }
}

// ---------------- encoder view (dot2-based GEMMs) ----------------
template<int NPAIR>
__device__ __forceinline__ void encode_view(
    int tid, int row0, int voff, int vidx,
    const _Float16 (*sT)[144], _Float16 (*hT)[HID],
    const h2* __restrict__ W1h, const float* __restrict__ b1,
    const h2* __restrict__ W2h, const float* __restrict__ Wg,
    _Float16* __restrict__ Yv, float* __restrict__ yg4f){
  // GEMM1: 32xHID = sT_v[32 x 2*NPAIR] @ W1
  {
    int c0 = (tid & 63)*4, rg = (tid >> 6)*8;
    float4 acc[8];
    #pragma unroll
    for(int i = 0; i < 8; i++) acc[i] = make_float4(0.f,0.f,0.f,0.f);
    for(int j = 0; j < NPAIR; j++){
      uint4 wv = *(const uint4*)&W1h[j*HID + c0];
      h2 w0 = bch2(wv.x), w1 = bch2(wv.y), w2 = bch2(wv.z), w3 = bch2(wv.w);
      #pragma unroll
      for(int i = 0; i < 8; i++){
        h2 s2 = *(const h2*)&sT[rg + i][voff + 2*j];
        acc[i].x = fdot2(s2, w0, acc[i].x);
        acc[i].y = fdot2(s2, w1, acc[i].y);
        acc[i].z = fdot2(s2, w2, acc[i].z);
        acc[i].w = fdot2(s2, w3, acc[i].w);
      }
    }
    float4 bb = *(const float4*)&b1[c0];
    #pragma unroll
    for(int i = 0; i < 8; i++){
      float h0 = fmaxf(acc[i].x + bb.x, 0.f);
      float h1 = fmaxf(acc[i].y + bb.y, 0.f);
      float h2v = fmaxf(acc[i].z + bb.z, 0.f);
      float h3 = fmaxf(acc[i].w + bb.w, 0.f);
      h2 t0; t0[0] = (_Float16)h0; t0[1] = (_Float16)h1;
      h2 t1; t1[0] = (_Float16)h2v; t1[1] = (_Float16)h3;
      *(h2*)&hT[rg + i][c0]     = t0;
      *(h2*)&hT[rg + i][c0 + 2] = t1;
    }
  }
  __syncthreads();
  // GEMM2: 32xLAT = hT[32xHID] @ W2; Y fp16; yg = Y @ Wg
  {
    int c0 = (tid & 31)*4, rg = (tid >> 5)*4;
    float4 acc[4];
    #pragma unroll
    for(int i = 0; i < 4; i++) acc[i] = make_float4(0.f,0.f,0.f,0.f);
    for(int k2 = 0; k2 < HID/2; k2++){
      uint4 wv = *(const uint4*)&W2h[k2*LAT + c0];
      h2 w0 = bch2(wv.x), w1 = bch2(wv.y), w2 = bch2(wv.z), w3 = bch2(wv.w);
      #pragma unroll
      for(int i = 0; i < 4; i++){
        h2 hh = *(const h2*)&hT[rg + i][2*k2];
        acc[i].x = fdot2(hh, w0, acc[i].x);
        acc[i].y = fdot2(hh, w1, acc[i].y);
        acc[i].z = fdot2(hh, w2, acc[i].z);
        acc[i].w = fdot2(hh, w3, acc[i].w);
      }
    }
    float4 wg = *(const float4*)&Wg[c0];
    #pragma unroll
    for(int i = 0; i < 4; i++){
      int row = row0 + rg + i;
      h2 t0; t0[0] = (_Float16)acc[i].x; t0[1] = (_Float16)acc[i].y;
      h2 t1; t1[0] = (_Float16)acc[i].z; t1[1] = (_Float16)acc[i].w;
      *(h2*)&Yv[(size_t)row*LAT + c0]     = t0;
      *(h2*)&Yv[(size_t)row*LAT + c0 + 2] = t1;
      float p = acc[i].x*wg.x + acc[i].y*wg.y + acc[i].z*wg.z + acc[i].w*wg.w;
      #pragma unroll
      for(int off = 16; off >= 1; off >>= 1) p += __shfl_xor(p, off);
      if((tid & 31) == 0) yg4f[(size_t)row*4 + vidx] = p;
    }
  }
  __syncthreads();
}

// ---------------- fused spmm1 + 3 encoders ----------------
__global__ __launch_bounds__(256, 5) void k_encfused(
    const int* __restrict__ row_ptr, const int* __restrict__ cols_s, const _Float16* __restrict__ vals_s,
    const _Float16* __restrict__ xc,
    const h2* __restrict__ w1p, const float* __restrict__ bp1, const h2* __restrict__ w2p, const float* __restrict__ Wgp,
    const h2* __restrict__ w1f, const float* __restrict__ bf1, const h2* __restrict__ w2f, const float* __restrict__ Wgf,
    const h2* __restrict__ w1n, const float* __restrict__ bn1, const h2* __restrict__ w2n, const float* __restrict__ Wgn,
    _Float16* __restrict__ Yp, _Float16* __restrict__ Yf, _Float16* __restrict__ Yn,
    float* __restrict__ yg4f){
  __shared__ _Float16 sT[32][144];   // 9.2 KB
  __shared__ _Float16 hT[32][HID];   // 16 KB
  int tid = threadIdx.x;
  int lane = tid & 63, wid = tid >> 6;
  int row0 = blockIdx.x * 32;
  bool has2 = (lane < 16);

  // phase 0: gather-spmm rows -> sT (fp16)
  for(int rr8 = 0; rr8 < 8; rr8++){
    int r = row0 + wid*8 + rr8;
    int start = row_ptr[r], end = row_ptr[r+1];
    float a0 = 0.f, a1 = 0.f, a2 = 0.f;
    for(int j0 = start; j0 < end; j0 += 64){
      int m = end - j0; if(m > 64) m = 64;
      int mycol = 0; float myval = 0.f;
      if(lane < m){ mycol = cols_s[j0 + lane]; myval = (float)vals_s[j0 + lane]; }
      int mpad = (m + 3) & ~3;
      for(int k = 0; k < mpad; k += 4){
        #pragma unroll
        for(int q = 0; q < 4; q++){
          int c = __shfl(mycol, k + q);
          float v = __shfl(myval, k + q);
          const _Float16* xr = &xc[(size_t)c*144];
          float x0 = (float)xr[lane];
          float x1 = (float)xr[64 + lane];
          a0 = fmaf(v, x0, a0);
          a1 = fmaf(v, x1, a1);
          if(has2){
            float x2 = (float)xr[128 + lane];
            a2 = fmaf(v, x2, a2);
          }
        }
      }
    }
    int rr = wid*8 + rr8;
    sT[rr][lane]      = (_Float16)a0;
    sT[rr][64 + lane] = (_Float16)a1;
    if(has2) sT[rr][128 + lane] = (_Float16)a2;
  }
  __syncthreads();

  encode_view<31>(tid, row0, 0,   0, sT, hT, w1p, bp1, w2p, Wgp, Yp, yg4f);
  encode_view<19>(tid, row0, 62,  1, sT, hT, w1f, bf1, w2f, Wgf, Yf, yg4f);
  encode_view<19>(tid, row0, 100, 2, sT, hT, w1n, bn1, w2n, Wgn, Yn, yg4f);
}

// ---------------- fused spmm2 + gate softmax + combine -> z (fp16) ----------------
__global__ __launch_bounds__(256) void k_spmm2f(
    const int* __restrict__ row_ptr, const int* __restrict__ cols_s, const _Float16* __restrict__ vals_s,
    const _Float16* __restrict__ Yp, const _Float16* __restrict__ Yf, const _Float16* __restrict__ Yn,
    const float4* __restrict__ yg4, const float* __restrict__ c3,
    const float* __restrict__ b2p, const float* __restrict__ b2f, const float* __restrict__ b2n,
    _Float16* __restrict__ z){
  int tid = threadIdx.x;
  int hl = tid & 31;
  int base = tid & 32;                 // broadcast base within wave
  int r = blockIdx.x*8 + (tid >> 5);   // 8 rows/block, half-wave per row
  int start = row_ptr[r], end = row_ptr[r+1];
  int o = hl*4;
  float ap0=0,ap1=0,ap2=0,ap3=0, af0=0,af1=0,af2=0,af3=0, an0=0,an1=0,an2=0,an3=0;
  float scp=0.f, scf=0.f, scn=0.f;
  for(int j0 = start; j0 < end; j0 += 32){
    int m = end - j0; if(m > 32) m = 32;
    int mycol = 0; float myval = 0.f;
    if(hl < m){
      mycol = cols_s[j0 + hl];
      myval = (float)vals_s[j0 + hl];
      float4 g = yg4[mycol];
      scp = fmaf(myval, g.x, scp);
      scf = fmaf(myval, g.y, scf);
      scn = fmaf(myval, g.z, scn);
    }
    int mpad = (m + 1) & ~1;
    for(int k = 0; k < mpad; k += 2){
      #pragma unroll
      for(int q = 0; q < 2; q++){
        int c = __shfl(mycol, base + k + q);
        float v = __shfl(myval, base + k + q);
        size_t b = (size_t)c*LAT + o;
        uint2 rp = *(const uint2*)&Yp[b];
        uint2 rf = *(const uint2*)&Yf[b];
        uint2 rn = *(const uint2*)&Yn[b];
        h2 pl = bch2(rp.x), ph = bch2(rp.y);
        h2 fl = bch2(rf.x), fh = bch2(rf.y);
        h2 nl = bch2(rn.x), nh = bch2(rn.y);
        ap0 = fmaf(v, (float)pl[0], ap0); ap1 = fmaf(v, (float)pl[1], ap1);
        ap2 = fmaf(v, (float)ph[0], ap2); ap3 = fmaf(v, (float)ph[1], ap3);
        af0 = fmaf(v, (float)fl[0], af0); af1 = fmaf(v, (float)fl[1], af1);
        af2 = fmaf(v, (float)fh[0], af2); af3 = fmaf(v, (float)fh[1], af3);
        an0 = fmaf(v, (float)nl[0], an0); an1 = fmaf(v, (float)nl[1], an1);
        an2 = fmaf(v, (float)nh[0], an2); an3 = fmaf(v, (float)nh[1], an3);
      }
    }
  }
  #pragma unroll
  for(int off = 16; off >= 1; off >>= 1){
    scp += __shfl_xor(scp, off);
    scf += __shfl_xor(scf, off);
    scn += __shfl_xor(scn, off);
  }
  float sp = scp + c3[0], sf = scf + c3[1], sn = scn + c3[2];
  float mx = fmaxf(sp, fmaxf(sf, sn));
  float ep = expf(sp - mx), ef = expf(sf - mx), en = expf(sn - mx);
  float inv = 1.f / (ep + ef + en);
  float A0 = ep*inv, A1 = ef*inv, A2 = en*inv;
  float4 bp = *(const float4*)&b2p[o];
  float4 bf = *(const float4*)&b2f[o];
  float4 bn = *(const float4*)&b2n[o];
  float z0 = A0*(ap0 + bp.x) + A1*(af0 + bf.x) + A2*(an0 + bn.x);
  float z1 = A0*(ap1 + bp.y) + A1*(af1 + bf.y) + A2*(an1 + bn.y);
  float z2 = A0*(ap2 + bp.z) + A1*(af2 + bf.z) + A2*(an2 + bn.z);
  float z3 = A0*(ap3 + bp.w) + A1*(af3 + bf.w) + A2*(an3 + bn.w);
  H4 outv;
  outv.h[0] = (_Float16)z0; outv.h[1] = (_Float16)z1;
  outv.h[2] = (_Float16)z2; outv.h[3] = (_Float16)z3;
  *(H4*)&z[(size_t)r*LAT + o] = outv;
}

// ---------------- edge decoder: MFMA, wave = feature region ----------------
// logits = relu(feats@Wd1+bd1)@Wd2+bd2 ; feats[e] = [zs | zd | zs*zd | |zs-zd|]
// Block: 4 waves, wave w owns k-range [w*128, w*128+128) (= region w).
// Wd1 (fp16) lives in registers as B-fragments, reused across edge tiles.
#define DEC_TILES (NE/16)
__global__ __launch_bounds__(256) void k_dec(
    const _Float16* __restrict__ z, const int* __restrict__ esrc, const int* __restrict__ edst,
    const float* __restrict__ Wd1, const float* __restrict__ bd1,
    const float* __restrict__ Wd2, const float* __restrict__ bd2, float* __restrict__ out){
  __shared__ float part[4][16][68];   // 17.4 KB (68 pad: kg-groups land 2-way not 4-way)
  int tid = threadIdx.x;
  int w  = tid >> 6;       // wave id = feature region
  int l  = tid & 63;
  int erow = l & 15;       // A-fragment row (edge within tile); also B col
  int kg   = l >> 4;       // k subgroup

  // B fragments: frag[kt][nt] GPR j = Wd1[w*128 + kt*32 + kg*8 + j][nt*16 + erow]
  f16x8 bfr[4][4];
  #pragma unroll
  for(int kt = 0; kt < 4; kt++){
    #pragma unroll
    for(int nt = 0; nt < 4; nt++){
      f16x8 bb;
      #pragma unroll
      for(int j = 0; j < 8; j++)
        bb[j] = (_Float16)Wd1[(w*128 + kt*32 + kg*8 + j)*64 + nt*16 + erow];
      bfr[kt][nt] = bb;
    }
  }

  int n0 = (tid & 15) * 4;   // epilogue: this thread's 4 hidden cols
  int e2 = tid >> 4;         // epilogue: this thread's edge
  float4 bb1 = *(const float4*)&bd1[n0];
  float4 w2v = *(const float4*)&Wd2[n0];
  float bias2 = bd2[0];

  for(int tile = blockIdx.x; tile < DEC_TILES; tile += gridDim.x){
    int e = tile*16 + erow;
    int si = esrc[e], di = edst[e];
    const f16x8* zs = (const f16x8*)&z[(size_t)si*LAT];
    const f16x8* zd = (const f16x8*)&z[(size_t)di*LAT];
    f16x8 afr[4];
    if(w == 0){
      #pragma unroll
      for(int kt = 0; kt < 4; kt++) afr[kt] = zs[kt*4 + kg];
    } else if(w == 1){
      #pragma unroll
      for(int kt = 0; kt < 4; kt++) afr[kt] = zd[kt*4 + kg];
    } else if(w == 2){
      #pragma unroll
      for(int kt = 0; kt < 4; kt++) afr[kt] = zs[kt*4 + kg] * zd[kt*4 + kg];
    } else {
      #pragma unroll
      for(int kt = 0; kt < 4; kt++){
        f16x8 d = zs[kt*4 + kg] - zd[kt*4 + kg];
        s16x8 m = __builtin_bit_cast(s16x8, d) & (short)0x7fff;
        afr[kt] = __builtin_bit_cast(f16x8, m);
      }
    }
    f32x4 zero = {0.f, 0.f, 0.f, 0.f};
    f32x4 acc[4] = {zero, zero, zero, zero};
    #pragma unroll
    for(int kt = 0; kt < 4; kt++){
      #pragma unroll
      for(int nt = 0; nt < 4; nt++)
        acc[nt] = __builtin_amdgcn_mfma_f32_16x16x32_f16(afr[kt], bfr[kt][nt], acc[nt], 0, 0, 0);
    }
    // partials -> LDS: D row = kg*4+j (edge), col = nt*16+erow (hidden)
    #pragma unroll
    for(int nt = 0; nt < 4; nt++){
      #pragma unroll
      for(int j = 0; j < 4; j++)
        part[w][kg*4 + j][nt*16 + erow] = acc[nt][j];
    }
    __syncthreads();
    // reduce over regions + relu + dot Wd2; 16 threads per edge
    float s0 = part[0][e2][n0+0] + part[1][e2][n0+0] + part[2][e2][n0+0] + part[3][e2][n0+0];
    float s1 = part[0][e2][n0+1] + part[1][e2][n0+1] + part[2][e2][n0+1] + part[3][e2][n0+1];
    float s2 = part[0][e2][n0+2] + part[1][e2][n0+2] + part[2][e2][n0+2] + part[3][e2][n0+2];
    float s3 = part[0][e2][n0+3] + part[1][e2][n0+3] + part[2][e2][n0+3] + part[3][e2][n0+3];
    float p = fmaxf(s0 + bb1.x, 0.f)*w2v.x + fmaxf(s1 + bb1.y, 0.f)*w2v.y
            + fmaxf(s2 + bb1.z, 0.f)*w2v.z + fmaxf(s3 + bb1.w, 0.f)*w2v.w;
    #pragma unroll
    for(int off = 1; off < 16; off <<= 1) p += __shfl_xor(p, off);
    if((tid & 15) == 0) out[tile*16 + e2] = p + bias2;
    __syncthreads();   // protect part[] before next tile overwrites
  }
}

// ---------------- host ----------------
extern "C" void kernel_launch(void* const* d_in, const int* in_sizes, int n_in,
                              void* d_out, int out_size, void* d_ws, size_t ws_size,
                              hipStream_t stream) {
  const float* xp  = (const float*)d_in[0];
  const float* xf  = (const float*)d_in[1];
  const float* xn  = (const float*)d_in[2];
  const int* arows = (const int*)d_in[3];
  const int* acols = (const int*)d_in[4];
  const float* avals = (const float*)d_in[5];
  const int* esrc  = (const int*)d_in[6];
  const int* edst  = (const int*)d_in[7];
  const float* Wp1 = (const float*)d_in[8];  const float* bp1 = (const float*)d_in[9];
  const float* Wp2 = (const float*)d_in[10]; const float* bp2 = (const float*)d_in[11];
  const float* Wf1 = (const float*)d_in[12]; const float* bf1 = (const float*)d_in[13];
  const float* Wf2 = (const float*)d_in[14]; const float* bf2w = (const float*)d_in[15];
  const float* Wn1 = (const float*)d_in[16]; const float* bn1 = (const float*)d_in[17];
  const float* Wn2 = (const float*)d_in[18]; const float* bn2 = (const float*)d_in[19];
  const float* Wgp = (const float*)d_in[20]; const float* bgp = (const float*)d_in[21];
  const float* Wgf = (const float*)d_in[22]; const float* bgf = (const float*)d_in[23];
  const float* Wgn = (const float*)d_in[24]; const float* bgn = (const float*)d_in[25];
  const float* Wd1 = (const float*)d_in[26]; const float* bd1 = (const float*)d_in[27];
  const float* Wd2 = (const float*)d_in[28]; const float* bd2 = (const float*)d_in[29];
  float* out = (float*)d_out;
  (void)in_sizes; (void)n_in; (void)out_size; (void)ws_size;

  char* base = (char*)d_ws;
  size_t off = 0;
  auto alloc = [&](size_t nbytes) -> char* {
    off = (off + 255) & ~(size_t)255;
    char* p = base + off;
    off += nbytes;
    return p;
  };
  int*      row_ptr = (int*)     alloc((size_t)(Nn + 1) * 4);   // 0.8 MB
  int*      cols_s  = (int*)     alloc((size_t)NNZV * 4);       // 25.6 MB
  _Float16* vals_s  = (_Float16*)alloc((size_t)NNZV * 2);       // 12.8 MB
  _Float16* xcat    = (_Float16*)alloc((size_t)Nn * 144 * 2);   // 57.6 MB (aliases z + CSR temps)
  _Float16* Yp      = (_Float16*)alloc((size_t)Nn * LAT * 2);   // 51.2 MB
  _Float16* Yf      = (_Float16*)alloc((size_t)Nn * LAT * 2);   // 51.2 MB
  _Float16* Yn      = (_Float16*)alloc((size_t)Nn * LAT * 2);   // 51.2 MB
  float*    yg4     = (float*)   alloc((size_t)Nn * 4 * 4);     // 3.2 MB
  float*    c3      = (float*)   alloc(256);
  h2* w1p = (h2*)alloc(7936*4);  h2* w1f = (h2*)alloc(4864*4);  h2* w1n = (h2*)alloc(4864*4);
  h2* w2p = (h2*)alloc(16384*4); h2* w2f = (h2*)alloc(16384*4); h2* w2n = (h2*)alloc(16384*4);
  // z aliases xcat (xcat dead after k_encfused); CSR temps alias xcat (dead before k_xpack)
  _Float16* z = xcat;
  int* cur  = (int*)((char*)xcat);
  int* incl = (int*)((char*)xcat + 1000000);
  int* bsum = (int*)((char*)xcat + 2000000);
  // total ws: ~254 MB

  int NB = (Nn + 511) / 512;

  k_zero   <<<(Nn + 255)/256, 256, 0, stream>>>(cur);
  k_count  <<<(NNZV + 255)/256, 256, 0, stream>>>(arows, cur);
  k_scan_block<<<NB, 512, 0, stream>>>(cur, incl, bsum);
  k_scan_bsum<<<1, 512, 0, stream>>>(bsum, NB);
  k_finish <<<(Nn + 255)/256, 256, 0, stream>>>(incl, bsum, row_ptr);
  k_initcur<<<(Nn + 255)/256, 256, 0, stream>>>(row_ptr, cur);
  k_scatter<<<(NNZV + 255)/256, 256, 0, stream>>>(arows, acols, avals, cur, cols_s, vals_s);

  k_xpack<<<(Nn*36 + 255)/256, 256, 0, stream>>>(xp, xf, xn, xcat);
  k_wpack<<<(66816 + 255)/256, 256, 0, stream>>>(Wp1, Wf1, Wn1, Wp2, Wf2, Wn2,
                                                 w1p, w1f, w1n, w2p, w2f, w2n);
  k_const<<<1, 64, 0, stream>>>(bp2, Wgp, bgp, bf2w, Wgf, bgf, bn2, Wgn, bgn, c3);

  k_encfused<<<Nn/32, 256, 0, stream>>>(row_ptr, cols_s, vals_s, xcat,
      w1p, bp1, w2p, Wgp,  w1f, bf1, w2f, Wgf,  w1n, bn1, w2n, Wgn,
      Yp, Yf, Yn, yg4);

  k_spmm2f<<<Nn/8, 256, 0, stream>>>(row_ptr, cols_s, vals_s, Yp, Yf, Yn,
      (const float4*)yg4, c3, bp2, bf2w, bn2, z);

  k_dec<<<2048, 256, 0, stream>>>(z, esrc, edst, Wd1, bd1, Wd2, bd2, out);
}